// Round 5
// baseline (686.347 us; speedup 1.0000x reference)
//
#include <hip/hip_runtime.h>
#include <hip/hip_bf16.h>

#define NN    20000
#define BB    2
#define FINN  256
#define EE    320000
#define EDIMM 64
#define HH    8
#define CC    32
#define MROWS (NN * BB)   // 40000
#define NCAT  1024        // q|k|v|r concatenated, 4*256

typedef __bf16 bf16x8 __attribute__((ext_vector_type(8)));
typedef float  floatx4 __attribute__((ext_vector_type(4)));

// ---------------------------------------------------------------------------
// Input dtype detection (flag=1 -> bf16, flag=0 -> fp32). Kept as a guard;
// all evidence says fp32 (forced-bf16 read NaN'd in R1).
// ---------------------------------------------------------------------------
__global__ void detect_dtype(const unsigned int* __restrict__ x,
                             int* __restrict__ flag) {
  __shared__ int cnt;
  if (threadIdx.x == 0) cnt = 0;
  __syncthreads();
  int c = 0;
  for (int i = threadIdx.x; i < 16384; i += 256) {
    unsigned w = x[i];
    unsigned le = (w >> 7) & 0xFF;
    if ((le >= 0x70 && le <= 0x8F) || (w & 0xFFFFu) == 0) c++;
  }
  atomicAdd(&cnt, c);
  __syncthreads();
  if (threadIdx.x == 0) *flag = (cnt > 8192) ? 1 : 0;
}

__device__ __forceinline__ float loadf(const void* p, size_t i, int bf) {
  return bf ? __bfloat162float(((const __hip_bfloat16*)p)[i])
            : ((const float*)p)[i];
}

// ---------------------------------------------------------------------------
// Transpose 4x [256,256] weights into wt[1024][256] bf16 (n-major) + biases.
// ---------------------------------------------------------------------------
__global__ void prep_weights(const void* __restrict__ Wq,
                             const void* __restrict__ Wk,
                             const void* __restrict__ Wv,
                             const void* __restrict__ Wr,
                             const void* __restrict__ bq,
                             const void* __restrict__ bk,
                             const void* __restrict__ bv,
                             const void* __restrict__ br,
                             const int* __restrict__ dflag,
                             __hip_bfloat16* __restrict__ wt,
                             float* __restrict__ bcat) {
  int bf = *dflag;
  int n = blockIdx.x;            // 0..1023
  int sel = n >> 8, col = n & 255;
  const void* W  = (sel == 0) ? Wq : (sel == 1) ? Wk : (sel == 2) ? Wv : Wr;
  const void* Bv = (sel == 0) ? bq : (sel == 1) ? bk : (sel == 2) ? bv : br;
  int t = threadIdx.x;           // k index
  wt[n * 256 + t] = __float2bfloat16(loadf(W, (size_t)t * 256 + col, bf));
  if (t == 0) bcat[n] = loadf(Bv, col, bf);
}

// wesum[h][d] = sum_c We[d][h*32+c]  (collapses E x 256 edge GEMM to E x 8)
__global__ void prep_wesum(const void* __restrict__ We,
                           const int* __restrict__ dflag,
                           float* __restrict__ wesum) {
  int bf = *dflag;
  int i = threadIdx.x;           // 0..511
  int h = i >> 6, d = i & 63;
  float s = 0.f;
  for (int c = 0; c < 32; ++c) s += loadf(We, (size_t)d * 256 + h * 32 + c, bf);
  wesum[h * 64 + d] = s;
}

__global__ void zero_ints(int* __restrict__ p, int n) {
  int i = blockIdx.x * 256 + threadIdx.x;
  if (i < n) p[i] = 0;
}

// ---------------------------------------------------------------------------
// Fused q|k|v|r GEMM: qkvr[M=40000][1024] fp32 = x[M][256] @ wt^T + bcat
// 64x64 tile, BK=32, mfma_f32_16x16x32_bf16, 2x2 waves of 32x32.
// (Cross-validated against the VALU GEMM in R3/R4 — identical results.)
// ---------------------------------------------------------------------------
__global__ __launch_bounds__(256) void gemm_qkvr(
    const void* __restrict__ x,      // [MROWS][256] fp32 (or bf16)
    const __bf16* __restrict__ wt,   // [1024][256]  (B^T: n-major)
    const float* __restrict__ bcat,  // [1024]
    const int* __restrict__ dflag,
    float* __restrict__ out) {       // [MROWS][1024] fp32
  const int LSTR = 56;
  __shared__ __attribute__((aligned(16))) __bf16 As[64 * LSTR];
  __shared__ __attribute__((aligned(16))) __bf16 Bs[64 * LSTR];

  int bf = *dflag;
  int m0 = blockIdx.y * 64;
  int n0 = blockIdx.x * 64;
  int t = threadIdx.x;
  int w = t >> 6, l = t & 63;
  int wm = w >> 1, wn = w & 1;
  int lr = l & 15, lq = l >> 4;

  int sr = t >> 2;                   // staging row 0..63
  int sc = (t & 3) * 8;              // staging col 0,8,16,24

  const __bf16* gb = wt + (n0 + sr) * 256 + sc;
  __bf16* sa = &As[sr * LSTR + sc];
  __bf16* sb = &Bs[sr * LSTR + sc];

  floatx4 acc[2][2] = {};

  for (int ks = 0; ks < 8; ++ks) {
    bf16x8 av;
    if (bf) {
      av = *(const bf16x8*)((const __bf16*)x + (size_t)(m0 + sr) * 256 + sc + ks * 32);
    } else {
      const float* xf = (const float*)x + (size_t)(m0 + sr) * 256 + sc + ks * 32;
      float4 f0 = *(const float4*)xf;
      float4 f1 = *(const float4*)(xf + 4);
      av[0] = (__bf16)f0.x; av[1] = (__bf16)f0.y;
      av[2] = (__bf16)f0.z; av[3] = (__bf16)f0.w;
      av[4] = (__bf16)f1.x; av[5] = (__bf16)f1.y;
      av[6] = (__bf16)f1.z; av[7] = (__bf16)f1.w;
    }
    bf16x8 bv = *(const bf16x8*)(gb + ks * 32);
    *(bf16x8*)sa = av;
    *(bf16x8*)sb = bv;
    __syncthreads();
    bf16x8 af0 = *(const bf16x8*)&As[(32 * wm + lr) * LSTR + lq * 8];
    bf16x8 af1 = *(const bf16x8*)&As[(32 * wm + 16 + lr) * LSTR + lq * 8];
    bf16x8 bf0 = *(const bf16x8*)&Bs[(32 * wn + lr) * LSTR + lq * 8];
    bf16x8 bf1 = *(const bf16x8*)&Bs[(32 * wn + 16 + lr) * LSTR + lq * 8];
    acc[0][0] = __builtin_amdgcn_mfma_f32_16x16x32_bf16(af0, bf0, acc[0][0], 0, 0, 0);
    acc[0][1] = __builtin_amdgcn_mfma_f32_16x16x32_bf16(af0, bf1, acc[0][1], 0, 0, 0);
    acc[1][0] = __builtin_amdgcn_mfma_f32_16x16x32_bf16(af1, bf0, acc[1][0], 0, 0, 0);
    acc[1][1] = __builtin_amdgcn_mfma_f32_16x16x32_bf16(af1, bf1, acc[1][1], 0, 0, 0);
    __syncthreads();
  }

  // C/D: col = lane&15, row = (lane>>4)*4 + reg
  for (int mt = 0; mt < 2; ++mt)
    for (int nt = 0; nt < 2; ++nt)
      for (int r = 0; r < 4; ++r) {
        int gr = m0 + 32 * wm + 16 * mt + lq * 4 + r;
        int gc = n0 + 32 * wn + 16 * nt + lr;
        out[(size_t)gr * 1024 + gc] = acc[mt][nt][r] + bcat[gc];
      }
}

// ---------------------------------------------------------------------------
// esum[e][h] = edata[e] . wesum[h] — one thread per edge, wesum in LDS.
// ---------------------------------------------------------------------------
__global__ __launch_bounds__(256) void esum2_kernel(
    const void* __restrict__ edata,
    const float* __restrict__ wesum,
    const int* __restrict__ dflag,
    float* __restrict__ esum) {
  __shared__ float wl[512];
  int t = threadIdx.x;
  wl[t] = wesum[t];
  wl[t + 256] = wesum[t + 256];
  __syncthreads();
  int bf = *dflag;
  int e = blockIdx.x * 256 + t;
  if (e >= EE) return;
  float acc[8] = {};
  if (!bf) {
    const float* row = (const float*)edata + (size_t)e * 64;
    for (int d = 0; d < 64; d += 4) {
      float4 v = *(const float4*)(row + d);
      for (int h = 0; h < 8; ++h) {
        const float* w = &wl[h * 64 + d];
        acc[h] += v.x * w[0] + v.y * w[1] + v.z * w[2] + v.w * w[3];
      }
    }
  } else {
    const __hip_bfloat16* row = (const __hip_bfloat16*)edata + (size_t)e * 64;
    for (int d = 0; d < 64; ++d) {
      float v = __bfloat162float(row[d]);
      for (int h = 0; h < 8; ++h) acc[h] += v * wl[h * 64 + d];
    }
  }
  for (int h = 0; h < 8; ++h) esum[(size_t)e * 8 + h] = acc[h];
}

// ---------------------------------------------------------------------------
// CSR build: histogram, scan (1 block), scatter
// ---------------------------------------------------------------------------
__global__ void hist_kernel(const int* __restrict__ dst, int* __restrict__ counts) {
  int e = blockIdx.x * 256 + threadIdx.x;
  if (e < EE) atomicAdd(&counts[dst[e]], 1);
}

__global__ void scan_kernel(const int* __restrict__ counts,
                            int* __restrict__ offsets,
                            int* __restrict__ cursor) {
  __shared__ int part[256];
  int t = threadIdx.x;
  const int per = (NN + 255) / 256;   // 79
  int lo = t * per, hi = min(lo + per, NN);
  int s = 0;
  for (int i = lo; i < hi; ++i) s += counts[i];
  part[t] = s;
  __syncthreads();
  for (int off = 1; off < 256; off <<= 1) {
    int v = (t >= off) ? part[t - off] : 0;
    __syncthreads();
    part[t] += v;
    __syncthreads();
  }
  int base = (t == 0) ? 0 : part[t - 1];
  for (int i = lo; i < hi; ++i) {
    offsets[i] = base;
    cursor[i] = base;
    base += counts[i];
  }
  if (t == 255) offsets[NN] = base;
}

__global__ void scatter_kernel(const int* __restrict__ dst,
                               int* __restrict__ cursor,
                               int* __restrict__ sorted) {
  int e = blockIdx.x * 256 + threadIdx.x;
  if (e < EE) {
    int p = atomicAdd(&cursor[dst[e]], 1);
    sorted[p] = e;
  }
}

// ---------------------------------------------------------------------------
// Fused logits + online-softmax + V-aggregation + residual. One block per
// (dst,b); thread t owns channel t (head h = t>>5). QK dot via 5-step
// shfl_xor butterfly within each 32-lane head group. fp32 throughout.
// ---------------------------------------------------------------------------
__global__ __launch_bounds__(256) void aggregate_kernel(
    const float* __restrict__ qkvr,   // [MROWS][1024]: q|k|v|r
    const float* __restrict__ esum,   // [E][8]
    const int* __restrict__ offsets,
    const int* __restrict__ sorted,
    const int* __restrict__ src,
    float* __restrict__ out) {        // [MROWS][256] fp32
  int nb = blockIdx.x;           // n*2 + b
  int b = nb & 1, n = nb >> 1;
  int t = threadIdx.x;
  int h = t >> 5;
  int beg = offsets[n], end = offsets[n + 1];

  float qv = qkvr[(size_t)nb * 1024 + t];   // q[dst][t]

  float m = -INFINITY, z = 0.f, acc = 0.f;
  for (int i = beg; i < end; ++i) {
    int e = sorted[i];
    int s = src[e];
    const float* row = qkvr + (size_t)(s * 2 + b) * 1024;
    float kv = row[256 + t];
    float vv = row[512 + t];
    float part = kv * qv;
    part += __shfl_xor(part, 16, 64);
    part += __shfl_xor(part, 8, 64);
    part += __shfl_xor(part, 4, 64);
    part += __shfl_xor(part, 2, 64);
    part += __shfl_xor(part, 1, 64);
    float l = part * 0.17677669529663687f + esum[(size_t)e * 8 + h];
    float mn = fmaxf(m, l);
    float fac = __expf(m - mn);               // exp(-inf)=0 handles first iter
    float p = __expf(l - mn);
    z = z * fac + p;
    acc = acc * fac + p * vv;
    m = mn;
  }
  float o = (end > beg) ? (acc / z) : 0.f;
  o += qkvr[(size_t)nb * 1024 + 768 + t];    // + x@Wr + br
  out[(size_t)nb * 256 + t] = o;
}

// ---------------------------------------------------------------------------
extern "C" void kernel_launch(void* const* d_in, const int* in_sizes, int n_in,
                              void* d_out, int out_size, void* d_ws, size_t ws_size,
                              hipStream_t stream) {
  (void)in_sizes; (void)n_in; (void)out_size; (void)ws_size;
  const void* x     = d_in[0];
  const void* edata = d_in[1];
  const int* esrc   = (const int*)d_in[2];
  const int* edst   = (const int*)d_in[3];
  const void* Wq    = d_in[4];
  const void* bq    = d_in[5];
  const void* Wk    = d_in[6];
  const void* bk    = d_in[7];
  const void* Wv    = d_in[8];
  const void* bv    = d_in[9];
  const void* We    = d_in[10];
  const void* Wr    = d_in[11];
  const void* br    = d_in[12];
  float* out = (float*)d_out;     // fp32 output (reference returns fp32)

  // Small buffers first; qkvr (fp32, 163.8 MB) last. Total ~176 MB; the
  // R2==R3/R4 agreement proved ws_size >= ~197 MB.
  char* ws = (char*)d_ws;
  size_t off = 0;
  auto carve = [&](size_t bytes) -> void* {
    void* p = ws + off;
    off += (bytes + 255) & ~(size_t)255;
    return p;
  };
  int* dflag     = (int*)carve(4);
  int* counts    = (int*)carve((size_t)NN * 4);
  int* offsets   = (int*)carve((size_t)(NN + 1) * 4);
  int* cursor    = (int*)carve((size_t)NN * 4);
  int* sorted    = (int*)carve((size_t)EE * 4);               // 1.28 MB
  __hip_bfloat16* wt = (__hip_bfloat16*)carve((size_t)1024 * 256 * 2);
  float* bcat    = (float*)carve(1024 * 4);
  float* wesum   = (float*)carve(8 * 64 * 4);
  float* esum    = (float*)carve((size_t)EE * 8 * 4);         // 10.24 MB
  float* qkvr    = (float*)carve((size_t)MROWS * 1024 * 4);   // 163.84 MB

  detect_dtype<<<1, 256, 0, stream>>>((const unsigned int*)x, dflag);
  zero_ints<<<(NN + 255) / 256, 256, 0, stream>>>(counts, NN);
  prep_weights<<<NCAT, 256, 0, stream>>>(Wq, Wk, Wv, Wr, bq, bk, bv, br, dflag, wt, bcat);
  prep_wesum<<<1, 512, 0, stream>>>(We, dflag, wesum);
  hist_kernel<<<(EE + 255) / 256, 256, 0, stream>>>(edst, counts);
  scan_kernel<<<1, 256, 0, stream>>>(counts, offsets, cursor);
  scatter_kernel<<<(EE + 255) / 256, 256, 0, stream>>>(edst, cursor, sorted);
  gemm_qkvr<<<dim3(16, 625), 256, 0, stream>>>(x, (const __bf16*)wt, bcat, dflag, qkvr);
  esum2_kernel<<<(EE + 255) / 256, 256, 0, stream>>>(edata, wesum, dflag, esum);
  aggregate_kernel<<<NN * BB, 256, 0, stream>>>(qkvr, esum, offsets, sorted, esrc, out);
}

// Round 6
// 519.893 us; speedup vs baseline: 1.3202x; 1.3202x over previous
//
#include <hip/hip_runtime.h>
#include <hip/hip_bf16.h>

#define NN    20000
#define BB    2
#define EE    320000
#define MROWS (NN * BB)   // 40000

typedef __bf16 bf16x8 __attribute__((ext_vector_type(8)));
typedef float  floatx4 __attribute__((ext_vector_type(4)));

// Channel permutation of the 1024 fused output channels (c = head*32+chan):
//   j in [0,512):    c = j>>1;        j even -> k[c], j odd -> v[c]
//   j in [512,1024): c = (j-512)>>1;  j even -> q[c], j odd -> r[c]
// So a uint32 at row*512 + c       = (k[c] | v[c]<<16)  (bf16 pair)
//    a uint32 at row*512 + 256 + c = (q[c] | r[c]<<16)

// ---------------------------------------------------------------------------
// Weight transpose + permute: wt[1024][256] bf16, wt[j][k] = W_sel[k][col(j)].
// LDS-tiled so both global reads and writes are coalesced.
// ---------------------------------------------------------------------------
__global__ __launch_bounds__(256) void transpose_weights(
    const float* __restrict__ Wq, const float* __restrict__ Wk,
    const float* __restrict__ Wv, const float* __restrict__ Wr,
    __hip_bfloat16* __restrict__ wt) {
  __shared__ float TA[32][65];
  __shared__ float TB[32][65];
  int bt = blockIdx.x;                 // 0..15
  const float *A, *B;
  int c0, jbase;
  if (bt < 8) { A = Wk; B = Wv; c0 = 32 * bt;      jbase = 64 * bt; }
  else        { A = Wq; B = Wr; c0 = 32 * (bt-8);  jbase = 512 + 64 * (bt-8); }
  int t = threadIdx.x;
  int krow = t >> 2;                   // 0..63
  int cc = (t & 3) * 8;                // 0,8,16,24
  int sel = t >> 7;                    // write phase: 0->A, 1->B
  int u = t & 127;
  int ci = u >> 2;                     // 0..31
  int kk0 = (u & 3) * 16;              // 0,16,32,48

  for (int kt = 0; kt < 4; ++kt) {
    int k = kt * 64 + krow;
    float4 a0 = *(const float4*)(A + (size_t)k * 256 + c0 + cc);
    float4 a1 = *(const float4*)(A + (size_t)k * 256 + c0 + cc + 4);
    float4 b0 = *(const float4*)(B + (size_t)k * 256 + c0 + cc);
    float4 b1 = *(const float4*)(B + (size_t)k * 256 + c0 + cc + 4);
    __syncthreads();                   // previous write phase done
    TA[cc+0][krow]=a0.x; TA[cc+1][krow]=a0.y; TA[cc+2][krow]=a0.z; TA[cc+3][krow]=a0.w;
    TA[cc+4][krow]=a1.x; TA[cc+5][krow]=a1.y; TA[cc+6][krow]=a1.z; TA[cc+7][krow]=a1.w;
    TB[cc+0][krow]=b0.x; TB[cc+1][krow]=b0.y; TB[cc+2][krow]=b0.z; TB[cc+3][krow]=b0.w;
    TB[cc+4][krow]=b1.x; TB[cc+5][krow]=b1.y; TB[cc+6][krow]=b1.z; TB[cc+7][krow]=b1.w;
    __syncthreads();
    float (*T)[65] = sel ? TB : TA;
    int j = jbase + 2 * ci + sel;
    __hip_bfloat16* dst = wt + (size_t)j * 256 + kt * 64 + kk0;
    #pragma unroll
    for (int q = 0; q < 16; ++q) dst[q] = __float2bfloat16(T[ci][kk0 + q]);
  }
}

__global__ void prep_bias(const float* __restrict__ bq, const float* __restrict__ bk,
                          const float* __restrict__ bv, const float* __restrict__ br,
                          float* __restrict__ bcat) {
  int j = blockIdx.x * 256 + threadIdx.x;   // grid 4 x 256
  float val;
  if (j < 512) { int c = j >> 1;         val = (j & 1) ? bv[c] : bk[c]; }
  else         { int c = (j - 512) >> 1; val = (j & 1) ? br[c] : bq[c]; }
  bcat[j] = val;
}

// wesum[h][d] = sum_c We[d][h*32+c]
__global__ void prep_wesum(const float* __restrict__ We, float* __restrict__ wesum) {
  int i = threadIdx.x;           // 0..511
  int h = i >> 6, d = i & 63;
  float s = 0.f;
  for (int c = 0; c < 32; ++c) s += We[(size_t)d * 256 + h * 32 + c];
  wesum[h * 64 + d] = s;
}

__global__ void zero_ints(int* __restrict__ p, int n) {
  int i = blockIdx.x * 256 + threadIdx.x;
  if (i < n) p[i] = 0;
}

// ---------------------------------------------------------------------------
// Fused q|k|v|r GEMM, channel-permuted bf16 output.
// Tile M=64 x N=256 (x re-read only 4x), BK=32, 4 waves each 64x64 (4x4 frags).
// LDS row stride 40 elems (80 B): 16B-aligned frag reads, ~2-way banks (free).
// ---------------------------------------------------------------------------
__global__ __launch_bounds__(256) void gemm_qkvr(
    const float* __restrict__ x,     // [MROWS][256] fp32
    const __bf16* __restrict__ wt,   // [1024][256] bf16 (n-major, permuted)
    const float* __restrict__ bcat,  // [1024] permuted
    __hip_bfloat16* __restrict__ out) {  // [MROWS][1024] bf16 permuted
  const int LSTR = 40;
  __shared__ __attribute__((aligned(16))) __bf16 As[64 * LSTR];
  __shared__ __attribute__((aligned(16))) __bf16 Bs[256 * LSTR];

  int m0 = blockIdx.y * 64;
  int n0 = blockIdx.x * 256;
  int t = threadIdx.x;
  int w = t >> 6, l = t & 63;
  int lr = l & 15, lq = l >> 4;
  int ar = t >> 2, ac = (t & 3) * 8;   // A staging: row, col

  floatx4 acc[4][4] = {};              // [mt][nt]

  for (int ks = 0; ks < 8; ++ks) {
    const float* xp = x + (size_t)(m0 + ar) * 256 + ks * 32 + ac;
    float4 f0 = *(const float4*)xp;
    float4 f1 = *(const float4*)(xp + 4);
    bf16x8 av;
    av[0] = (__bf16)f0.x; av[1] = (__bf16)f0.y;
    av[2] = (__bf16)f0.z; av[3] = (__bf16)f0.w;
    av[4] = (__bf16)f1.x; av[5] = (__bf16)f1.y;
    av[6] = (__bf16)f1.z; av[7] = (__bf16)f1.w;
    const __bf16* wp = wt + (size_t)(n0 + t) * 256 + ks * 32;
    bf16x8 b0 = *(const bf16x8*)(wp);
    bf16x8 b1 = *(const bf16x8*)(wp + 8);
    bf16x8 b2 = *(const bf16x8*)(wp + 16);
    bf16x8 b3 = *(const bf16x8*)(wp + 24);
    __syncthreads();                   // previous step's frag reads done
    *(bf16x8*)&As[ar * LSTR + ac] = av;
    __bf16* bsr = &Bs[t * LSTR];
    *(bf16x8*)(bsr)      = b0;
    *(bf16x8*)(bsr + 8)  = b1;
    *(bf16x8*)(bsr + 16) = b2;
    *(bf16x8*)(bsr + 24) = b3;
    __syncthreads();
    bf16x8 af[4], bf_[4];
    #pragma unroll
    for (int mt = 0; mt < 4; ++mt)
      af[mt] = *(const bf16x8*)&As[(16 * mt + lr) * LSTR + lq * 8];
    #pragma unroll
    for (int nt = 0; nt < 4; ++nt)
      bf_[nt] = *(const bf16x8*)&Bs[(64 * w + 16 * nt + lr) * LSTR + lq * 8];
    #pragma unroll
    for (int mt = 0; mt < 4; ++mt)
      #pragma unroll
      for (int nt = 0; nt < 4; ++nt)
        acc[mt][nt] = __builtin_amdgcn_mfma_f32_16x16x32_bf16(af[mt], bf_[nt], acc[mt][nt], 0, 0, 0);
  }

  // C/D: col = lane&15, row = (lane>>4)*4 + reg
  #pragma unroll
  for (int mt = 0; mt < 4; ++mt)
    #pragma unroll
    for (int nt = 0; nt < 4; ++nt)
      #pragma unroll
      for (int r = 0; r < 4; ++r) {
        int gr = m0 + 16 * mt + lq * 4 + r;
        int gc = n0 + 64 * w + 16 * nt + lr;
        out[(size_t)gr * 1024 + gc] = __float2bfloat16(acc[mt][nt][r] + bcat[gc]);
      }
}

// ---------------------------------------------------------------------------
// esum[e][h] = edata[e] . wesum[h] — one thread per edge, wesum in LDS.
// ---------------------------------------------------------------------------
__global__ __launch_bounds__(256) void esum2_kernel(
    const float* __restrict__ edata,
    const float* __restrict__ wesum,
    float* __restrict__ esum) {
  __shared__ float wl[512];
  int t = threadIdx.x;
  wl[t] = wesum[t];
  wl[t + 256] = wesum[t + 256];
  __syncthreads();
  int e = blockIdx.x * 256 + t;
  if (e >= EE) return;
  float acc[8] = {};
  const float* row = edata + (size_t)e * 64;
  for (int d = 0; d < 64; d += 4) {
    float4 v = *(const float4*)(row + d);
    #pragma unroll
    for (int h = 0; h < 8; ++h) {
      const float* wv = &wl[h * 64 + d];
      acc[h] += v.x * wv[0] + v.y * wv[1] + v.z * wv[2] + v.w * wv[3];
    }
  }
  #pragma unroll
  for (int h = 0; h < 8; ++h) esum[(size_t)e * 8 + h] = acc[h];
}

// ---------------------------------------------------------------------------
// CSR build: histogram, scan (1 block), scatter
// ---------------------------------------------------------------------------
__global__ void hist_kernel(const int* __restrict__ dst, int* __restrict__ counts) {
  int e = blockIdx.x * 256 + threadIdx.x;
  if (e < EE) atomicAdd(&counts[dst[e]], 1);
}

__global__ void scan_kernel(const int* __restrict__ counts,
                            int* __restrict__ offsets,
                            int* __restrict__ cursor) {
  __shared__ int part[256];
  int t = threadIdx.x;
  const int per = (NN + 255) / 256;   // 79
  int lo = t * per, hi = min(lo + per, NN);
  int s = 0;
  for (int i = lo; i < hi; ++i) s += counts[i];
  part[t] = s;
  __syncthreads();
  for (int off = 1; off < 256; off <<= 1) {
    int v = (t >= off) ? part[t - off] : 0;
    __syncthreads();
    part[t] += v;
    __syncthreads();
  }
  int base = (t == 0) ? 0 : part[t - 1];
  for (int i = lo; i < hi; ++i) {
    offsets[i] = base;
    cursor[i] = base;
    base += counts[i];
  }
  if (t == 255) offsets[NN] = base;
}

__global__ void scatter_kernel(const int* __restrict__ dst,
                               int* __restrict__ cursor,
                               int* __restrict__ sorted) {
  int e = blockIdx.x * 256 + threadIdx.x;
  if (e < EE) {
    int p = atomicAdd(&cursor[dst[e]], 1);
    sorted[p] = e;
  }
}

// ---------------------------------------------------------------------------
// Fused logits + online-softmax + V-aggregation + residual, fp32 out.
// One block per (dst,b); thread t owns channel t (head h = t>>5).
// Edge/src indices staged through LDS (kills serial address chain); kv/esum
// prefetched 1 iteration ahead. k,v arrive packed in one uint32.
// ---------------------------------------------------------------------------
__global__ __launch_bounds__(256) void aggregate_kernel(
    const unsigned int* __restrict__ qkvr,  // [MROWS][512] uints (kv | qr pairs)
    const float* __restrict__ esum,         // [E][8]
    const int* __restrict__ offsets,
    const int* __restrict__ sorted,
    const int* __restrict__ src,
    float* __restrict__ out) {              // [MROWS][256] fp32
  __shared__ int se[128], ss[128];
  int nb = blockIdx.x;           // n*2 + b
  int b = nb & 1, n = nb >> 1;
  int t = threadIdx.x;
  int h = t >> 5;
  int beg = offsets[n], end = offsets[n + 1];

  unsigned qr = qkvr[(size_t)nb * 512 + 256 + t];
  float qv = __uint_as_float(qr << 16);            // q = low bf16
  float rv = __uint_as_float(qr & 0xFFFF0000u);    // r = high bf16

  float m = -INFINITY, z = 0.f, acc = 0.f;
  for (int base = beg; base < end; base += 128) {
    int chunk = min(128, end - base);
    __syncthreads();
    if (t < chunk) se[t] = sorted[base + t];
    __syncthreads();
    if (t < chunk) ss[t] = src[se[t]];
    __syncthreads();
    unsigned kv_n = qkvr[(size_t)(ss[0] * 2 + b) * 512 + t];
    float es_n = esum[(size_t)se[0] * 8 + h];
    for (int i = 0; i < chunk; ++i) {
      unsigned kv = kv_n;
      float es = es_n;
      if (i + 1 < chunk) {
        kv_n = qkvr[(size_t)(ss[i + 1] * 2 + b) * 512 + t];
        es_n = esum[(size_t)se[i + 1] * 8 + h];
      }
      float kf = __uint_as_float(kv << 16);
      float vf = __uint_as_float(kv & 0xFFFF0000u);
      float part = kf * qv;
      part += __shfl_xor(part, 16, 64);
      part += __shfl_xor(part, 8, 64);
      part += __shfl_xor(part, 4, 64);
      part += __shfl_xor(part, 2, 64);
      part += __shfl_xor(part, 1, 64);
      float lg = part * 0.17677669529663687f + es;
      float mn = fmaxf(m, lg);
      float fac = __expf(m - mn);               // exp(-inf)=0 handles first iter
      float p = __expf(lg - mn);
      z = z * fac + p;
      acc = acc * fac + p * vf;
      m = mn;
    }
  }
  float o = (z > 0.f) ? (acc / z) : 0.f;
  out[(size_t)nb * 256 + t] = o + rv;
}

// ---------------------------------------------------------------------------
extern "C" void kernel_launch(void* const* d_in, const int* in_sizes, int n_in,
                              void* d_out, int out_size, void* d_ws, size_t ws_size,
                              hipStream_t stream) {
  (void)in_sizes; (void)n_in; (void)out_size; (void)ws_size;
  const float* x     = (const float*)d_in[0];
  const float* edata = (const float*)d_in[1];
  const int* esrc    = (const int*)d_in[2];
  const int* edst    = (const int*)d_in[3];
  const float* Wq    = (const float*)d_in[4];
  const float* bq    = (const float*)d_in[5];
  const float* Wk    = (const float*)d_in[6];
  const float* bk    = (const float*)d_in[7];
  const float* Wv    = (const float*)d_in[8];
  const float* bv    = (const float*)d_in[9];
  const float* We    = (const float*)d_in[10];
  const float* Wr    = (const float*)d_in[11];
  const float* br    = (const float*)d_in[12];
  float* out = (float*)d_out;     // fp32 output

  char* ws = (char*)d_ws;
  size_t off = 0;
  auto carve = [&](size_t bytes) -> void* {
    void* p = ws + off;
    off += (bytes + 255) & ~(size_t)255;
    return p;
  };
  int* counts    = (int*)carve((size_t)NN * 4);
  int* offsets   = (int*)carve((size_t)(NN + 1) * 4);
  int* cursor    = (int*)carve((size_t)NN * 4);
  int* sorted    = (int*)carve((size_t)EE * 4);               // 1.28 MB
  __hip_bfloat16* wt = (__hip_bfloat16*)carve((size_t)1024 * 256 * 2);
  float* bcat    = (float*)carve(1024 * 4);
  float* wesum   = (float*)carve(8 * 64 * 4);
  float* esum    = (float*)carve((size_t)EE * 8 * 4);         // 10.24 MB
  __hip_bfloat16* qkvr = (__hip_bfloat16*)carve((size_t)MROWS * 1024 * 2); // 81.9 MB

  zero_ints<<<(NN + 255) / 256, 256, 0, stream>>>(counts, NN);
  transpose_weights<<<16, 256, 0, stream>>>(Wq, Wk, Wv, Wr, wt);
  prep_bias<<<4, 256, 0, stream>>>(bq, bk, bv, br, bcat);
  prep_wesum<<<1, 512, 0, stream>>>(We, wesum);
  hist_kernel<<<(EE + 255) / 256, 256, 0, stream>>>(edst, counts);
  scan_kernel<<<1, 256, 0, stream>>>(counts, offsets, cursor);
  scatter_kernel<<<(EE + 255) / 256, 256, 0, stream>>>(edst, cursor, sorted);
  gemm_qkvr<<<dim3(4, 625), 256, 0, stream>>>(x, (const __bf16*)wt, bcat, qkvr);
  esum2_kernel<<<(EE + 255) / 256, 256, 0, stream>>>(edata, wesum, esum);
  aggregate_kernel<<<NN * BB, 256, 0, stream>>>((const unsigned int*)qkvr, esum,
                                                offsets, sorted, esrc, out);
}